// Round 8
// baseline (26.023 us; speedup 1.0000x reference)
//
#include <hip/hip_runtime.h>

// GridMatch: A=8, B=8, N=2048, grid 640x480 per (a,b) image.
// Single fused kernel: per-image LDS hash + distributed padding fill +
// last-block-done emit (rocPRIM-style device-scope handshake).
#define AD 8
#define BD 8
#define NP 2048
#define MPTS (AD*BD*NP)            // 131072 points
#define NIMG (AD*BD)               // 64 images
#define HSZ 4096                   // LDS hash slots (max distinct cells/image = 4096)
#define RCAP 2048                  // max matches/image
#define NBLK 256                   // total blocks (64 hash + 192 fill)

// Match records, grouped by image. Fully rewritten every call.
__device__ int g_cnt[NIMG];
__device__ int g_rc[NIMG*RCAP];    // local cell index (x*gh + y) — row-major rank key
__device__ int g_rs[NIMG*RCAP];    // global src point id
__device__ int g_rd[NIMG*RCAP];    // global dst point id
__device__ int g_done;             // arrival counter; reset to 0 by last block

__global__ __launch_bounds__(256) void k_all(
    const float* __restrict__ ps, const float* __restrict__ pd,
    float* __restrict__ out,
    const int* __restrict__ ph, const int* __restrict__ pw,
    const int* __restrict__ pg) {
  __shared__ int hkey[HSZ];
  __shared__ int hsrc[HSZ];
  __shared__ int hdst[HSZ];
  __shared__ int lcnt;
  __shared__ int sflag;
  __shared__ int scnt[NIMG];
  __shared__ int soff[NIMG+1];

  int b = blockIdx.x, tid = threadIdx.x;
  int h = *ph, w = *pw, gs = *pg;
  int gh = h * gs, gw = w * gs;
  float sx = (float)((gw - 1) * 0.5);
  float sy = (float)((gh - 1) * 0.5);

  if (b >= NIMG) {
    // ---- fill blocks: pad the whole output (flat 294912 float4 range) ----
    // floats [0, 4*MPTS) = coord arrays -> 0; [4*MPTS, 8*MPTS) = bn/an -> -1;
    // [8*MPTS, 9*MPTS) = valid -> 0. In float4 units: -1 iff q in [2*MPTS/2 ... ]
    const float4 z  = make_float4(0.f, 0.f, 0.f, 0.f);
    const float4 m1 = make_float4(-1.f, -1.f, -1.f, -1.f);
    int pb = b - NIMG;                       // 0..191
    float4* o4 = (float4*)out;
#pragma unroll
    for (int k = 0; k < 6; ++k) {            // 192*256*6 = 294912 float4 exactly
      int q = (pb*6 + k)*256 + tid;
      o4[q] = (q >= MPTS && q < 2*MPTS) ? m1 : z;   // float4 idx MPTS..2M-1 = bn/an
    }
  } else {
    // ---- hash blocks: build per-image cell table in LDS ----
    for (int i = tid; i < HSZ; i += 256) { hkey[i] = -1; hsrc[i] = 0; hdst[i] = 0; }
    if (tid == 0) lcnt = 0;
    __syncthreads();

    auto insert = [&](float px, float py, int gid, int* field) {
      if (!(px >= -1.f && px <= 1.f && py >= -1.f && py <= 1.f)) return;
      int c = (int)((px + 1.f) * sx) * gh + (int)((py + 1.f) * sy);  // local row-major
      int i = (int)(((unsigned)c * 2654435761u) >> 20) & (HSZ - 1);
      while (true) {
        int k = atomicCAS(&hkey[i], -1, c);
        if (k == -1 || k == c) { atomicMax(&field[i], gid + 1); return; }
        i = (i + 1) & (HSZ - 1);
      }
    };

    const float4* sp = (const float4*)ps + b * (NP/2);
    const float4* dp = (const float4*)pd + b * (NP/2);
    int gbase = b * NP;
#pragma unroll
    for (int k = 0; k < NP/512; ++k) {       // 4 x 256 float4 = 2048 pts/side
      int f = k*256 + tid;
      float4 s2 = sp[f];
      insert(s2.x, s2.y, gbase + 2*f,     hsrc);
      insert(s2.z, s2.w, gbase + 2*f + 1, hsrc);
      float4 d2 = dp[f];
      insert(d2.x, d2.y, gbase + 2*f,     hdst);
      insert(d2.z, d2.w, gbase + 2*f + 1, hdst);
    }
    __syncthreads();

    for (int i = tid; i < HSZ; i += 256) {
      if (hkey[i] >= 0) {
        int s = hsrc[i], d = hdst[i];
        if (s > 0 && d > 0) {
          int slot = atomicAdd(&lcnt, 1);
          g_rc[b*RCAP + slot] = hkey[i];
          g_rs[b*RCAP + slot] = s - 1;
          g_rd[b*RCAP + slot] = d - 1;
        }
      }
    }
    __syncthreads();
    if (tid == 0) g_cnt[b] = lcnt;
  }

  // ---- arrival handshake: release this block's stores, count arrivals ----
  __syncthreads();                            // drains all waves' stores to L2
  if (tid == 0) {
    __threadfence();                          // device-scope release (L2 writeback)
    int old = atomicAdd(&g_done, 1);
    sflag = (old == NBLK - 1);
  }
  __syncthreads();
  if (!sflag) return;

  // ---- last block: acquire and emit all matched rows ----
  if (tid == 0) __threadfence();              // device-scope acquire
  __syncthreads();

  if (tid < NIMG) scnt[tid] = g_cnt[tid];
  __syncthreads();
  if (tid == 0) {
    int acc = 0;
    for (int i = 0; i < NIMG; ++i) { soff[i] = acc; acc += scnt[i]; }
    soff[NIMG] = acc;
    g_done = 0;                               // reset for next call
  }
  __syncthreads();
  int total = soff[NIMG];

  float fxm = (float)((double)(h - 1) / (double)(gh - 1));  // pairs with x (faithful)
  float fym = (float)((double)(w - 1) / (double)(gw - 1));

  float* out0 = out;               // src_coord_m [M,2]
  float* out1 = out + 2*MPTS;      // dst_coord_m [M,2]
  float* out2 = out + 4*MPTS;      // src_bn      [M,2]
  float* out3 = out + 6*MPTS;      // dst_an      [M,2]
  float* out4 = out + 8*MPTS;      // valid       [M]

  for (int r = tid; r < total; r += 256) {
    // locate image: soff[ab] <= r < soff[ab+1]
    int lo = 0, hi = NIMG;
    while (hi - lo > 1) { int mid = (lo + hi) >> 1; if (soff[mid] <= r) lo = mid; else hi = mid; }
    int ab = lo, j = r - soff[ab], cnt = scnt[ab];

    int ci = g_rc[ab*RCAP + j];
    int rank = soff[ab];
    for (int i = 0; i < cnt; ++i) rank += (int)(g_rc[ab*RCAP + i] < ci);  // cells unique
    int s = g_rs[ab*RCAP + j], d = g_rd[ab*RCAP + j];
    float2 a2 = ((const float2*)ps)[s];
    out0[2*rank]   = (a2.x + 1.f) * sx * fxm;
    out0[2*rank+1] = (a2.y + 1.f) * sy * fym;
    float2 b2 = ((const float2*)pd)[d];
    out1[2*rank]   = (b2.x + 1.f) * sx * fxm;
    out1[2*rank+1] = (b2.y + 1.f) * sy * fym;
    out2[2*rank]   = (float)((s / NP) % BD);
    out2[2*rank+1] = (float)(s % NP);
    out3[2*rank]   = (float)(d / (BD * NP));
    out3[2*rank+1] = (float)(d % NP);
    out4[rank]     = 1.f;
  }
}

extern "C" void kernel_launch(void* const* d_in, const int* in_sizes, int n_in,
                              void* d_out, int out_size, void* d_ws, size_t ws_size,
                              hipStream_t stream) {
  const float* ps = (const float*)d_in[0];
  const float* pd = (const float*)d_in[1];
  const int* ph = (const int*)d_in[2];
  const int* pw = (const int*)d_in[3];
  const int* pg = (const int*)d_in[4];
  float* out = (float*)d_out;

  k_all<<<NBLK, 256, 0, stream>>>(ps, pd, out, ph, pw, pg);
}